// Round 1
// baseline (2543.508 us; speedup 1.0000x reference)
//
#include <hip/hip_runtime.h>
#include <hip/hip_bf16.h>

// Problem: B=128, N=256, D=256, H=256.
// out = [weighted (B*N*D), attention (B*N*N)] fp32, each 8388608 elements.
// rho per batch via Gelfand: 12 normalized squarings (m=4096).

#define BM 64
#define BN 64
#define BK 16
#define NB 128
#define MAT 65536  // 256*256 per-batch matrix elements
#define BIG 8388608LL

// C[bz] = alpha * A[bz] * op(B[bz]) + bias ; op = B^T if TB (both row-major, inner dim K)
// alpha = 1 (scale_ptr null) or 1/s or 1/s^2 with s = scale_ptr[bz*scale_stride]
template<bool TB>
__global__ __launch_bounds__(256) void gemm_kernel(
    const float* __restrict__ A, const float* __restrict__ B, float* __restrict__ C,
    int M, int N, int K,
    long long sA, long long sB, long long sC,
    const float* __restrict__ bias,
    const float* __restrict__ scale_ptr, int scale_stride, int scale_pow)
{
  int bz = blockIdx.z;
  A += (long long)bz * sA;
  B += (long long)bz * sB;
  C += (long long)bz * sC;
  int m0 = blockIdx.y * BM;
  int n0 = blockIdx.x * BN;
  __shared__ float As[BK][BM + 1];
  __shared__ float Bs[BK][BN + 1];
  int t = threadIdx.x;
  int tx = t & 15, ty = t >> 4;
  float acc[4][4] = {};
  for (int k0 = 0; k0 < K; k0 += BK) {
    #pragma unroll
    for (int i = 0; i < 4; i++) {
      int e = t + i * 256;
      int m = e >> 4, kk = e & 15;
      As[kk][m] = A[(long long)(m0 + m) * K + k0 + kk];
    }
    if (TB) {
      #pragma unroll
      for (int i = 0; i < 4; i++) {
        int e = t + i * 256;
        int n = e >> 4, kk = e & 15;
        Bs[kk][n] = B[(long long)(n0 + n) * K + k0 + kk];
      }
    } else {
      #pragma unroll
      for (int i = 0; i < 4; i++) {
        int e = t + i * 256;
        int kk = e >> 6, n = e & 63;
        Bs[kk][n] = B[(long long)(k0 + kk) * N + n0 + n];
      }
    }
    __syncthreads();
    #pragma unroll
    for (int kk = 0; kk < BK; kk++) {
      float a[4], b[4];
      #pragma unroll
      for (int i = 0; i < 4; i++) a[i] = As[kk][ty * 4 + i];
      #pragma unroll
      for (int j = 0; j < 4; j++) b[j] = Bs[kk][tx * 4 + j];
      #pragma unroll
      for (int i = 0; i < 4; i++)
        #pragma unroll
        for (int j = 0; j < 4; j++)
          acc[i][j] = fmaf(a[i], b[j], acc[i][j]);
    }
    __syncthreads();
  }
  float alpha = 1.0f;
  if (scale_ptr) {
    float s = scale_ptr[bz * scale_stride];
    alpha = (scale_pow == 2) ? 1.0f / (s * s) : 1.0f / s;
  }
  #pragma unroll
  for (int i = 0; i < 4; i++) {
    long long r = m0 + ty * 4 + i;
    #pragma unroll
    for (int j = 0; j < 4; j++) {
      int c = n0 + tx * 4 + j;
      float v = acc[i][j] * alpha;
      if (bias) v += bias[c];
      C[r * N + c] = v;
    }
  }
}

// Frobenius norm per batch matrix; accumulate w*log(norm) into rho_acc.
__global__ __launch_bounds__(256) void reduce_norm_kernel(
    const float* __restrict__ A, float* __restrict__ snorm,
    float* __restrict__ rho_acc, float w, int init)
{
  int b = blockIdx.x;
  const float* M = A + (long long)b * MAT;
  int t = threadIdx.x;
  float s = 0.f;
  for (int i = t; i < MAT; i += 256) { float x = M[i]; s += x * x; }
  __shared__ float red[256];
  red[t] = s; __syncthreads();
  for (int off = 128; off > 0; off >>= 1) {
    if (t < off) red[t] += red[t + off];
    __syncthreads();
  }
  if (t == 0) {
    float nrm = sqrtf(red[0]);
    snorm[b] = nrm;
    float term = w * logf(nrm);
    rho_acc[b] = init ? term : rho_acc[b] + term;
  }
}

__global__ void finalize_rho(const float* __restrict__ rho_acc, float* __restrict__ rho_inv)
{
  int b = threadIdx.x;
  if (b < NB) rho_inv[b] = expf(-rho_acc[b]);  // 1/rho
}

__global__ __launch_bounds__(256) void scale_att_kernel(
    float* __restrict__ att, const float* __restrict__ rho_inv)
{
  long long idx = (long long)blockIdx.x * 256 + threadIdx.x;
  att[idx] *= rho_inv[idx >> 16];
}

__device__ __forceinline__ float block_sum(float x, float* red, int t)
{
  red[t] = x; __syncthreads();
  for (int off = 128; off > 0; off >>= 1) {
    if (t < off) red[t] += red[t + off];
    __syncthreads();
  }
  float r = red[0];
  __syncthreads();
  return r;
}

// torch spectral_norm power iteration: u=l2n(u0); 5x { v=l2n(W^T u); u=l2n(W v) }; sigma=u^T W v
__global__ __launch_bounds__(256) void sigma_kernel(
    const float* __restrict__ W, const float* __restrict__ u0, float* __restrict__ sigma)
{
  __shared__ float u[256], v[256], red[256];
  int t = threadIdx.x;
  const float eps = 1e-12f;
  float x = u0[t];
  float nrm = sqrtf(block_sum(x * x, red, t));
  u[t] = x / (nrm + eps);
  __syncthreads();
  for (int it = 0; it < 5; it++) {
    // v = l2norm(W^T u)
    float s = 0.f;
    for (int h = 0; h < 256; h++) s += W[h * 256 + t] * u[h];
    nrm = sqrtf(block_sum(s * s, red, t));
    v[t] = s / (nrm + eps);
    __syncthreads();
    // u = l2norm(W v)
    float r2 = 0.f;
    for (int d = 0; d < 256; d++) r2 += W[t * 256 + d] * v[d];
    nrm = sqrtf(block_sum(r2 * r2, red, t));
    u[t] = r2 / (nrm + eps);
    __syncthreads();
  }
  float wv = 0.f;
  for (int d = 0; d < 256; d++) wv += W[t * 256 + d] * v[d];
  float sg = block_sum(u[t] * wv, red, t);
  if (t == 0) sigma[0] = sg;
}

extern "C" void kernel_launch(void* const* d_in, const int* in_sizes, int n_in,
                              void* d_out, int out_size, void* d_ws, size_t ws_size,
                              hipStream_t stream)
{
  const float* x  = (const float*)d_in[0];
  const float* Wq = (const float*)d_in[1];
  const float* bq = (const float*)d_in[2];
  const float* Wk = (const float*)d_in[3];
  const float* bk = (const float*)d_in[4];
  const float* Wv = (const float*)d_in[5];
  const float* bv = (const float*)d_in[6];
  const float* u0 = (const float*)d_in[7];

  float* out      = (float*)d_out;
  float* weighted = out;           // [B,N,D]
  float* scores   = out + BIG;     // [B,N,N] -> becomes attention in place

  float* ws   = (float*)d_ws;
  float* qb   = ws;                // [B,N,H]
  float* kb   = ws + BIG;          // [B,N,H], reused as vals after scores
  float* snorm   = ws + 2 * BIG;   // [128]
  float* rho_acc = snorm + NB;     // [128]
  float* rho_inv = rho_acc + NB;   // [128]
  float* sigma   = rho_inv + NB;   // [1]

  dim3 blk(256);

  // sigma(Wv) power iteration
  sigma_kernel<<<1, 256, 0, stream>>>(Wv, u0, sigma);

  // q = x @ Wq^T + bq ; k = x @ Wk^T + bk   (M=32768 rows)
  gemm_kernel<true><<<dim3(4, 512, 1), blk, 0, stream>>>(x, Wq, qb, 32768, 256, 256,
      0, 0, 0, bq, nullptr, 0, 1);
  gemm_kernel<true><<<dim3(4, 512, 1), blk, 0, stream>>>(x, Wk, kb, 32768, 256, 256,
      0, 0, 0, bk, nullptr, 0, 1);

  // scores[b] = q[b] @ k[b]^T  (into d_out attention region)
  gemm_kernel<true><<<dim3(4, 4, NB), blk, 0, stream>>>(qb, kb, scores, 256, 256, 256,
      MAT, MAT, MAT, nullptr, nullptr, 0, 1);

  // vals = (x @ Wv^T)/sigma + bv  (kb reusable now)
  float* vals = kb;
  gemm_kernel<true><<<dim3(4, 512, 1), blk, 0, stream>>>(x, Wv, vals, 32768, 256, 256,
      0, 0, 0, bv, sigma, 0, 1);

  // Gelfand: 12 normalized squarings, ping-pong between weighted region and qb
  const int KSQ = 12;
  float w = 1.0f;
  const float* cin = scores;
  for (int i = 0; i < KSQ; i++) {
    reduce_norm_kernel<<<NB, 256, 0, stream>>>(cin, snorm, rho_acc, w, i == 0 ? 1 : 0);
    float* cout = (i % 2 == 0) ? weighted : qb;
    gemm_kernel<false><<<dim3(4, 4, NB), blk, 0, stream>>>(cin, cin, cout, 256, 256, 256,
        MAT, MAT, MAT, nullptr, snorm, 1, 2);
    cin = cout;
    w *= 0.5f;
  }
  reduce_norm_kernel<<<NB, 256, 0, stream>>>(cin, snorm, rho_acc, w, 0);
  finalize_rho<<<1, 128, 0, stream>>>(rho_acc, rho_inv);

  // attention = scores / rho (in place in d_out)
  scale_att_kernel<<<32768, blk, 0, stream>>>(scores, rho_inv);

  // weighted = attention @ vals (overwrites scratch region of d_out chunk 1)
  gemm_kernel<false><<<dim3(4, 4, NB), blk, 0, stream>>>(scores, vals, weighted, 256, 256, 256,
      MAT, MAT, MAT, nullptr, nullptr, 0, 1);
}

// Round 2
// 652.856 us; speedup vs baseline: 3.8960x; 3.8960x over previous
//
#include <hip/hip_runtime.h>
#include <hip/hip_bf16.h>

// B=128, N=256, D=H=256. out = [weighted (B*N*D), attention (B*N*N)] fp32.
// rho per batch via Gelfand: 12 normalized squarings (m=4096), norms fused
// into GEMM epilogues. All GEMMs: split-bf16 (hi+lo) 3-MFMA fp32-accurate.

#define NB 128
#define MAT 65536
#define BIG 8388608LL

typedef __attribute__((ext_vector_type(4))) float floatx4;
typedef __attribute__((ext_vector_type(4))) float f4v;
typedef __attribute__((ext_vector_type(8))) short short8v;
typedef __attribute__((ext_vector_type(4))) short short4v;

__device__ __forceinline__ short f2bf(float x) {
  union { float f; unsigned u; } v; v.f = x;
  unsigned r = v.u + 0x7fff + ((v.u >> 16) & 1);
  return (short)(r >> 16);
}
__device__ __forceinline__ float bf2f(short h) {
  union { unsigned u; float f; } v; v.u = ((unsigned)(unsigned short)h) << 16; return v.f;
}

// C[bz] = alpha * A[bz] @ B[bz](^T) + bias, optional fused Frobenius norm^2.
// TB=true : B stored [N][K] row-major (k contiguous) - weights, k-for-scores.
// TB=false: B stored [K][N] row-major - squarings, weighted.
// smode: 0 none, 1 alpha=1/scale[bz*sstride], 2 alpha=scale[bz*sstride].
// All dims fixed: N=256, K=256, lda=ldb=ldc=256. M = gridDim.y*128.
template<bool TB>
__global__ __launch_bounds__(256) void gemm_mfma(
    const float* __restrict__ A, const float* __restrict__ B, float* __restrict__ C,
    long long sA, long long sB, long long sC,
    const float* __restrict__ bias,
    const float* __restrict__ scale_ptr, int sstride, int smode,
    float* __restrict__ norm_out)
{
  __shared__ short sAhi[128 * 32], sAlo[128 * 32];
  __shared__ short sBhi[128 * 40], sBlo[128 * 40];

  const int bz = blockIdx.z;
  A += (long long)bz * sA;
  B += (long long)bz * sB;
  C += (long long)bz * sC;
  const int m0 = blockIdx.y * 128;
  const int n0 = blockIdx.x * 128;

  const int t = threadIdx.x;
  const int lane = t & 63;
  const int wave = t >> 6;
  const int wm = wave >> 1, wn = wave & 1;
  const int q = lane >> 4, c16 = lane & 15;

  floatx4 acc[4][4];
  #pragma unroll
  for (int i = 0; i < 4; i++)
    #pragma unroll
    for (int j = 0; j < 4; j++)
      acc[i][j] = (floatx4){0.f, 0.f, 0.f, 0.f};

  for (int k0 = 0; k0 < 256; k0 += 32) {
    // ---- stage A tile [128][32] ----
    #pragma unroll
    for (int i = 0; i < 4; i++) {
      int f = t + i * 256;
      int row = f >> 3, c4 = f & 7;
      f4v v = *(const f4v*)(A + (long long)(m0 + row) * 256 + k0 + c4 * 4);
      short4v h, l;
      #pragma unroll
      for (int e = 0; e < 4; e++) {
        short hh = f2bf(v[e]);
        h[e] = hh;
        l[e] = f2bf(v[e] - bf2f(hh));
      }
      *(short4v*)&sAhi[row * 32 + c4 * 4] = h;
      *(short4v*)&sAlo[row * 32 + c4 * 4] = l;
    }
    if (TB) {
      // ---- stage B tile from [N][K]: same pattern as A ----
      #pragma unroll
      for (int i = 0; i < 4; i++) {
        int f = t + i * 256;
        int row = f >> 3, c4 = f & 7;
        f4v v = *(const f4v*)(B + (long long)(n0 + row) * 256 + k0 + c4 * 4);
        short4v h, l;
        #pragma unroll
        for (int e = 0; e < 4; e++) {
          short hh = f2bf(v[e]);
          h[e] = hh;
          l[e] = f2bf(v[e] - bf2f(hh));
        }
        *(short4v*)&sBhi[row * 40 + c4 * 4] = h;
        *(short4v*)&sBlo[row * 40 + c4 * 4] = l;
      }
      __syncthreads();
    } else {
      // ---- stage B tile from [K][N] via in-LDS fp32 transpose ----
      __shared__ float sT[32 * 132];
      #pragma unroll
      for (int i = 0; i < 4; i++) {
        int f = t + i * 256;
        int kk = f >> 5, n4 = f & 31;
        f4v v = *(const f4v*)(B + (long long)(k0 + kk) * 256 + n0 + n4 * 4);
        *(f4v*)&sT[kk * 132 + n4 * 4] = v;
      }
      __syncthreads();
      int n = t & 127, kh = t >> 7;
      short8v h0, h1, l0, l1;
      #pragma unroll
      for (int j = 0; j < 8; j++) {
        float x0 = sT[(kh * 16 + j) * 132 + n];
        float x1 = sT[(kh * 16 + 8 + j) * 132 + n];
        short a0 = f2bf(x0), a1 = f2bf(x1);
        h0[j] = a0; l0[j] = f2bf(x0 - bf2f(a0));
        h1[j] = a1; l1[j] = f2bf(x1 - bf2f(a1));
      }
      *(short8v*)&sBhi[n * 40 + kh * 16] = h0;
      *(short8v*)&sBhi[n * 40 + kh * 16 + 8] = h1;
      *(short8v*)&sBlo[n * 40 + kh * 16] = l0;
      *(short8v*)&sBlo[n * 40 + kh * 16 + 8] = l1;
      __syncthreads();
    }

    // ---- fragments + 3-MFMA split accumulate ----
    short8v ah[4], al[4], bh[4], bl[4];
    #pragma unroll
    for (int fi = 0; fi < 4; fi++) {
      int r = wm * 64 + fi * 16 + c16;
      ah[fi] = *(short8v*)&sAhi[r * 32 + q * 8];
      al[fi] = *(short8v*)&sAlo[r * 32 + q * 8];
    }
    #pragma unroll
    for (int fj = 0; fj < 4; fj++) {
      int r = wn * 64 + fj * 16 + c16;
      bh[fj] = *(short8v*)&sBhi[r * 40 + q * 8];
      bl[fj] = *(short8v*)&sBlo[r * 40 + q * 8];
    }
    #pragma unroll
    for (int fi = 0; fi < 4; fi++)
      #pragma unroll
      for (int fj = 0; fj < 4; fj++) {
        acc[fi][fj] = __builtin_amdgcn_mfma_f32_16x16x32_bf16(al[fi], bh[fj], acc[fi][fj], 0, 0, 0);
        acc[fi][fj] = __builtin_amdgcn_mfma_f32_16x16x32_bf16(ah[fi], bl[fj], acc[fi][fj], 0, 0, 0);
        acc[fi][fj] = __builtin_amdgcn_mfma_f32_16x16x32_bf16(ah[fi], bh[fj], acc[fi][fj], 0, 0, 0);
      }
    __syncthreads();
  }

  // ---- epilogue ----
  float alpha = 1.0f;
  if (smode == 1) alpha = 1.0f / scale_ptr[bz * sstride];
  else if (smode == 2) alpha = scale_ptr[bz * sstride];

  float ssq = 0.f;
  #pragma unroll
  for (int fi = 0; fi < 4; fi++) {
    #pragma unroll
    for (int fj = 0; fj < 4; fj++) {
      int col = n0 + wn * 64 + fj * 16 + c16;
      float bb = bias ? bias[col] : 0.f;
      #pragma unroll
      for (int r = 0; r < 4; r++) {
        int row = m0 + wm * 64 + fi * 16 + q * 4 + r;
        float v = acc[fi][fj][r] * alpha + bb;
        C[(long long)row * 256 + col] = v;
        ssq += v * v;
      }
    }
  }

  if (norm_out) {
    float* red = (float*)sAhi;  // reuse LDS (all waves past final barrier)
    red[t] = ssq;
    __syncthreads();
    for (int off = 128; off > 0; off >>= 1) {
      if (t < off) red[t] += red[t + off];
      __syncthreads();
    }
    if (t == 0) atomicAdd(&norm_out[bz], red[0]);
  }
}

__global__ void zero_kernel(float* __restrict__ p, int n) {
  int i = blockIdx.x * 256 + threadIdx.x;
  if (i < n) p[i] = 0.f;
}

__global__ void finalize_rho(const float* __restrict__ norm2, float* __restrict__ rho_inv) {
  int b = threadIdx.x;
  if (b < NB) {
    float acc = 0.f, w = 1.0f;
    for (int i = 0; i <= 12; i++) {
      acc += w * 0.5f * logf(norm2[i * NB + b]);
      w *= 0.5f;
    }
    rho_inv[b] = expf(-acc);
  }
}

__global__ __launch_bounds__(256) void scale_att_kernel(
    float* __restrict__ att, const float* __restrict__ rho_inv)
{
  long long idx = (long long)blockIdx.x * 256 + threadIdx.x;
  att[idx] *= rho_inv[idx >> 16];
}

__device__ __forceinline__ float block_sum(float x, float* red, int t)
{
  red[t] = x; __syncthreads();
  for (int off = 128; off > 0; off >>= 1) {
    if (t < off) red[t] += red[t + off];
    __syncthreads();
  }
  float r = red[0];
  __syncthreads();
  return r;
}

__global__ __launch_bounds__(256) void sigma_kernel(
    const float* __restrict__ W, const float* __restrict__ u0, float* __restrict__ sigma)
{
  __shared__ float u[256], v[256], red[256];
  int t = threadIdx.x;
  const float eps = 1e-12f;
  float x = u0[t];
  float nrm = sqrtf(block_sum(x * x, red, t));
  u[t] = x / (nrm + eps);
  __syncthreads();
  for (int it = 0; it < 5; it++) {
    float s = 0.f;
    for (int h = 0; h < 256; h++) s += W[h * 256 + t] * u[h];
    nrm = sqrtf(block_sum(s * s, red, t));
    v[t] = s / (nrm + eps);
    __syncthreads();
    float r2 = 0.f;
    for (int d = 0; d < 256; d++) r2 += W[t * 256 + d] * v[d];
    nrm = sqrtf(block_sum(r2 * r2, red, t));
    u[t] = r2 / (nrm + eps);
    __syncthreads();
  }
  float wv = 0.f;
  for (int d = 0; d < 256; d++) wv += W[t * 256 + d] * v[d];
  float sg = block_sum(u[t] * wv, red, t);
  if (t == 0) sigma[0] = sg;
}

extern "C" void kernel_launch(void* const* d_in, const int* in_sizes, int n_in,
                              void* d_out, int out_size, void* d_ws, size_t ws_size,
                              hipStream_t stream)
{
  const float* x  = (const float*)d_in[0];
  const float* Wq = (const float*)d_in[1];
  const float* bq = (const float*)d_in[2];
  const float* Wk = (const float*)d_in[3];
  const float* bk = (const float*)d_in[4];
  const float* Wv = (const float*)d_in[5];
  const float* bv = (const float*)d_in[6];
  const float* u0 = (const float*)d_in[7];

  float* out      = (float*)d_out;
  float* wout     = out;           // [B,N,D] weighted (also chain scratch)
  float* scores   = out + BIG;     // [B,N,N] -> attention in place

  float* ws      = (float*)d_ws;
  float* qb      = ws;             // [B,N,H] q, then chain scratch
  float* kb      = ws + BIG;       // [B,N,H] k, then vals
  float* norm2   = ws + 2 * BIG;   // [13][128]
  float* sigma   = norm2 + 13 * NB;
  float* rho_inv = sigma + 1;      // [128]

  dim3 blk(256);

  zero_kernel<<<7, blk, 0, stream>>>(norm2, 13 * NB);
  sigma_kernel<<<1, blk, 0, stream>>>(Wv, u0, sigma);

  // q = x @ Wq^T + bq ; k = x @ Wk^T + bk
  gemm_mfma<true><<<dim3(2, 256, 1), blk, 0, stream>>>(x, Wq, qb, 0, 0, 0,
      bq, nullptr, 0, 0, nullptr);
  gemm_mfma<true><<<dim3(2, 256, 1), blk, 0, stream>>>(x, Wk, kb, 0, 0, 0,
      bk, nullptr, 0, 0, nullptr);

  // scores[b] = q[b] @ k[b]^T, fused norm -> slot 0
  gemm_mfma<true><<<dim3(2, 2, NB), blk, 0, stream>>>(qb, kb, scores, MAT, MAT, MAT,
      nullptr, nullptr, 0, 0, norm2);

  // vals = (x @ Wv^T)/sigma + bv -> kb (k no longer needed)
  gemm_mfma<true><<<dim3(2, 256, 1), blk, 0, stream>>>(x, Wv, kb, 0, 0, 0,
      bv, sigma, 0, 1, nullptr);

  // Gelfand chain: 12 normalized squarings, fused norms -> slots 1..12
  const float* cur = scores;
  for (int i = 0; i < 12; i++) {
    float* cout = (i & 1) ? qb : wout;
    gemm_mfma<false><<<dim3(2, 2, NB), blk, 0, stream>>>(cur, cur, cout, MAT, MAT, MAT,
        nullptr, norm2 + i * NB, 1, 1, norm2 + (i + 1) * NB);
    cur = cout;
  }
  finalize_rho<<<1, 128, 0, stream>>>(norm2, rho_inv);

  // attention = scores / rho (in place in d_out)
  scale_att_kernel<<<32768, blk, 0, stream>>>(scores, rho_inv);

  // weighted = attention @ vals
  gemm_mfma<false><<<dim3(2, 2, NB), blk, 0, stream>>>(scores, kb, wout, MAT, MAT, MAT,
      nullptr, nullptr, 0, 0, nullptr);
}

// Round 3
// 614.372 us; speedup vs baseline: 4.1400x; 1.0626x over previous
//
#include <hip/hip_runtime.h>
#include <hip/hip_bf16.h>

// B=128, N=256, D=H=256. out = [weighted (B*N*D), attention (B*N*N)] fp32.
// rho per batch via Gelfand: 12 normalized squarings (m=4096), norms fused
// into GEMM epilogues. All GEMMs: split-bf16 (hi+lo) 3-MFMA fp32-accurate.
// Batched GEMMs use XCD-aware swizzle (each batch's tiles pinned to one XCD
// so the squaring chain ping-pongs inside per-XCD L2).

#define NB 128
#define MAT 65536
#define BIG 8388608LL

typedef __attribute__((ext_vector_type(4))) float floatx4;
typedef __attribute__((ext_vector_type(4))) float f4v;
typedef __attribute__((ext_vector_type(8))) short short8v;
typedef __attribute__((ext_vector_type(4))) short short4v;

__device__ __forceinline__ short f2bf(float x) {
  union { float f; unsigned u; } v; v.f = x;
  unsigned r = v.u + 0x7fff + ((v.u >> 16) & 1);
  return (short)(r >> 16);
}
__device__ __forceinline__ float bf2f(short h) {
  union { unsigned u; float f; } v; v.u = ((unsigned)(unsigned short)h) << 16; return v.f;
}

// C[bz] = alpha * A[bz] @ B[bz](^T) + bias, optional fused Frobenius norm^2,
// optional fused attention write (att_out = A * att_scale[bz], from n0==0 blocks).
// TB=true : B stored [N][K] (k contiguous). TB=false: B stored [K][N].
// smode: 0 alpha=1, 1 alpha=1/scale[bz*sstride], 2 alpha=scale[bz*sstride].
// BATCHED: grid (512,1,1); lin&7 -> XCD pin; 16 batches per XCD.
// else: grid (2, M/128, 1).
template<bool TB, bool BATCHED>
__global__ __launch_bounds__(256) void gemm_mfma(
    const float* __restrict__ A, const float* __restrict__ B, float* __restrict__ C,
    long long sA, long long sB, long long sC,
    const float* __restrict__ bias,
    const float* __restrict__ scale_ptr, int sstride, int smode,
    float* __restrict__ norm_out,
    float* __restrict__ att_out, const float* __restrict__ att_scale)
{
  __shared__ short sAhi[128 * 32], sAlo[128 * 32];
  __shared__ short sBhi[128 * 40], sBlo[128 * 40];

  int bz, m0, n0;
  if (BATCHED) {
    int lin = blockIdx.x;
    int xcd = lin & 7;
    int s = lin >> 3;            // 0..63
    bz = xcd * 16 + (s >> 2);    // 16 batches per XCD, stable across launches
    int tile = s & 3;
    m0 = (tile >> 1) * 128;
    n0 = (tile & 1) * 128;
  } else {
    bz = blockIdx.z;
    m0 = blockIdx.y * 128;
    n0 = blockIdx.x * 128;
  }
  A += (long long)bz * sA;
  B += (long long)bz * sB;
  C += (long long)bz * sC;

  const int t = threadIdx.x;
  const int lane = t & 63;
  const int wave = t >> 6;
  const int wm = wave >> 1, wn = wave & 1;
  const int q = lane >> 4, c16 = lane & 15;

  float rinv_att = 0.f;
  const bool do_att = (att_out != nullptr) && (n0 == 0);
  if (do_att) rinv_att = att_scale[bz];

  floatx4 acc[4][4];
  #pragma unroll
  for (int i = 0; i < 4; i++)
    #pragma unroll
    for (int j = 0; j < 4; j++)
      acc[i][j] = (floatx4){0.f, 0.f, 0.f, 0.f};

  for (int k0 = 0; k0 < 256; k0 += 32) {
    // ---- stage A tile [128][32] ----
    #pragma unroll
    for (int i = 0; i < 4; i++) {
      int f = t + i * 256;
      int row = f >> 3, c4 = f & 7;
      f4v v = *(const f4v*)(A + (long long)(m0 + row) * 256 + k0 + c4 * 4);
      if (do_att)
        *(f4v*)(att_out + (long long)bz * MAT + (long long)(m0 + row) * 256 + k0 + c4 * 4)
            = v * rinv_att;
      short4v h, l;
      #pragma unroll
      for (int e = 0; e < 4; e++) {
        short hh = f2bf(v[e]);
        h[e] = hh;
        l[e] = f2bf(v[e] - bf2f(hh));
      }
      *(short4v*)&sAhi[row * 32 + c4 * 4] = h;
      *(short4v*)&sAlo[row * 32 + c4 * 4] = l;
    }
    if (TB) {
      // ---- stage B tile from [N][K] ----
      #pragma unroll
      for (int i = 0; i < 4; i++) {
        int f = t + i * 256;
        int row = f >> 3, c4 = f & 7;
        f4v v = *(const f4v*)(B + (long long)(n0 + row) * 256 + k0 + c4 * 4);
        short4v h, l;
        #pragma unroll
        for (int e = 0; e < 4; e++) {
          short hh = f2bf(v[e]);
          h[e] = hh;
          l[e] = f2bf(v[e] - bf2f(hh));
        }
        *(short4v*)&sBhi[row * 40 + c4 * 4] = h;
        *(short4v*)&sBlo[row * 40 + c4 * 4] = l;
      }
      __syncthreads();
    } else {
      // ---- stage B tile from [K][N] via in-LDS fp32 transpose ----
      __shared__ float sT[32 * 132];
      #pragma unroll
      for (int i = 0; i < 4; i++) {
        int f = t + i * 256;
        int kk = f >> 5, n4 = f & 31;
        f4v v = *(const f4v*)(B + (long long)(k0 + kk) * 256 + n0 + n4 * 4);
        *(f4v*)&sT[kk * 132 + n4 * 4] = v;
      }
      __syncthreads();
      int n = t & 127, kh = t >> 7;
      short8v h0, h1, l0, l1;
      #pragma unroll
      for (int j = 0; j < 8; j++) {
        float x0 = sT[(kh * 16 + j) * 132 + n];
        float x1 = sT[(kh * 16 + 8 + j) * 132 + n];
        short a0 = f2bf(x0), a1 = f2bf(x1);
        h0[j] = a0; l0[j] = f2bf(x0 - bf2f(a0));
        h1[j] = a1; l1[j] = f2bf(x1 - bf2f(a1));
      }
      *(short8v*)&sBhi[n * 40 + kh * 16] = h0;
      *(short8v*)&sBhi[n * 40 + kh * 16 + 8] = h1;
      *(short8v*)&sBlo[n * 40 + kh * 16] = l0;
      *(short8v*)&sBlo[n * 40 + kh * 16 + 8] = l1;
      __syncthreads();
    }

    // ---- fragments + 3-MFMA split accumulate ----
    short8v ah[4], al[4], bh[4], bl[4];
    #pragma unroll
    for (int fi = 0; fi < 4; fi++) {
      int r = wm * 64 + fi * 16 + c16;
      ah[fi] = *(short8v*)&sAhi[r * 32 + q * 8];
      al[fi] = *(short8v*)&sAlo[r * 32 + q * 8];
    }
    #pragma unroll
    for (int fj = 0; fj < 4; fj++) {
      int r = wn * 64 + fj * 16 + c16;
      bh[fj] = *(short8v*)&sBhi[r * 40 + q * 8];
      bl[fj] = *(short8v*)&sBlo[r * 40 + q * 8];
    }
    #pragma unroll
    for (int fi = 0; fi < 4; fi++)
      #pragma unroll
      for (int fj = 0; fj < 4; fj++) {
        acc[fi][fj] = __builtin_amdgcn_mfma_f32_16x16x32_bf16(al[fi], bh[fj], acc[fi][fj], 0, 0, 0);
        acc[fi][fj] = __builtin_amdgcn_mfma_f32_16x16x32_bf16(ah[fi], bl[fj], acc[fi][fj], 0, 0, 0);
        acc[fi][fj] = __builtin_amdgcn_mfma_f32_16x16x32_bf16(ah[fi], bh[fj], acc[fi][fj], 0, 0, 0);
      }
    __syncthreads();
  }

  // ---- epilogue ----
  float alpha = 1.0f;
  if (smode == 1) alpha = 1.0f / scale_ptr[bz * sstride];
  else if (smode == 2) alpha = scale_ptr[bz * sstride];

  float ssq = 0.f;
  #pragma unroll
  for (int fi = 0; fi < 4; fi++) {
    #pragma unroll
    for (int fj = 0; fj < 4; fj++) {
      int col = n0 + wn * 64 + fj * 16 + c16;
      float bb = bias ? bias[col] : 0.f;
      #pragma unroll
      for (int r = 0; r < 4; r++) {
        int row = m0 + wm * 64 + fi * 16 + q * 4 + r;
        float v = acc[fi][fj][r] * alpha + bb;
        C[(long long)row * 256 + col] = v;
        ssq += v * v;
      }
    }
  }

  if (norm_out) {
    float* red = (float*)sAhi;
    red[t] = ssq;
    __syncthreads();
    for (int off = 128; off > 0; off >>= 1) {
      if (t < off) red[t] += red[t + off];
      __syncthreads();
    }
    if (t == 0) atomicAdd(&norm_out[bz], red[0]);
  }
}

__global__ void zero_kernel(float* __restrict__ p, int n) {
  int i = blockIdx.x * 256 + threadIdx.x;
  if (i < n) p[i] = 0.f;
}

__global__ void finalize_rho(const float* __restrict__ norm2, float* __restrict__ rho_inv) {
  int b = threadIdx.x;
  if (b < NB) {
    float acc = 0.f, w = 1.0f;
    for (int i = 0; i <= 12; i++) {
      acc += w * 0.5f * logf(norm2[i * NB + b]);
      w *= 0.5f;
    }
    rho_inv[b] = expf(-acc);
  }
}

__device__ __forceinline__ float block_sum(float x, float* red, int t)
{
  red[t] = x; __syncthreads();
  for (int off = 128; off > 0; off >>= 1) {
    if (t < off) red[t] += red[t + off];
    __syncthreads();
  }
  float r = red[0];
  __syncthreads();
  return r;
}

// Power iteration: u=l2n(u0); 5x { v=l2n(W^T u); u=l2n(W v) }; sigma=u^T W v.
// v-direction: 8 row-groups x 32 lanes owning 8 cols each (coalesced f4 loads),
// u-direction: per-thread row dot (f4, L1/L2-served).
__global__ __launch_bounds__(256) void sigma_kernel(
    const float* __restrict__ W, const float* __restrict__ u0, float* __restrict__ sigma)
{
  __shared__ float u[256], v[256], red[2048];
  int t = threadIdx.x;
  int g = t >> 5, c = t & 31;
  const float eps = 1e-12f;
  float x = u0[t];
  float nrm = sqrtf(block_sum(x * x, red, t));
  u[t] = x / (nrm + eps);
  __syncthreads();
  for (int it = 0; it < 5; it++) {
    // v = l2n(W^T u)
    float p[8] = {0.f,0.f,0.f,0.f,0.f,0.f,0.f,0.f};
    #pragma unroll 4
    for (int i = 0; i < 32; i++) {
      int h = g * 32 + i;
      float uh = u[h];
      f4v w0 = *(const f4v*)(W + h * 256 + c * 8);
      f4v w1 = *(const f4v*)(W + h * 256 + c * 8 + 4);
      #pragma unroll
      for (int e = 0; e < 4; e++) { p[e] += w0[e] * uh; p[4 + e] += w1[e] * uh; }
    }
    #pragma unroll
    for (int e = 0; e < 8; e++) red[g * 256 + c * 8 + e] = p[e];
    __syncthreads();
    float s = 0.f;
    #pragma unroll
    for (int gg = 0; gg < 8; gg++) s += red[gg * 256 + t];
    __syncthreads();
    nrm = sqrtf(block_sum(s * s, red, t));
    v[t] = s / (nrm + eps);
    __syncthreads();
    // u = l2n(W v)
    float r2 = 0.f;
    #pragma unroll 8
    for (int i = 0; i < 64; i++) {
      f4v w = *(const f4v*)(W + t * 256 + i * 4);
      r2 += w[0] * v[i*4] + w[1] * v[i*4+1] + w[2] * v[i*4+2] + w[3] * v[i*4+3];
    }
    nrm = sqrtf(block_sum(r2 * r2, red, t));
    u[t] = r2 / (nrm + eps);
    __syncthreads();
  }
  float wv = 0.f;
  #pragma unroll 8
  for (int i = 0; i < 64; i++) {
    f4v w = *(const f4v*)(W + t * 256 + i * 4);
    wv += w[0] * v[i*4] + w[1] * v[i*4+1] + w[2] * v[i*4+2] + w[3] * v[i*4+3];
  }
  float sg = block_sum(u[t] * wv, red, t);
  if (t == 0) sigma[0] = sg;
}

extern "C" void kernel_launch(void* const* d_in, const int* in_sizes, int n_in,
                              void* d_out, int out_size, void* d_ws, size_t ws_size,
                              hipStream_t stream)
{
  const float* x  = (const float*)d_in[0];
  const float* Wq = (const float*)d_in[1];
  const float* bq = (const float*)d_in[2];
  const float* Wk = (const float*)d_in[3];
  const float* bk = (const float*)d_in[4];
  const float* Wv = (const float*)d_in[5];
  const float* bv = (const float*)d_in[6];
  const float* u0 = (const float*)d_in[7];

  float* out  = (float*)d_out;
  float* out0 = out;             // weighted output region (chain scratch first)
  float* out1 = out + BIG;       // attention output region (chain scratch first)

  float* ws      = (float*)d_ws;
  float* scores_buf = ws;        // [B,N,N] raw scores (lives until final GEMM)
  float* vals_buf   = ws + BIG;  // [B,N,D] vals
  float* norm2   = ws + 2 * BIG; // [13][128]
  float* sigma   = norm2 + 13 * NB;
  float* rho_inv = sigma + 1;    // [128]

  dim3 blk(256);

  zero_kernel<<<7, blk, 0, stream>>>(norm2, 13 * NB);
  sigma_kernel<<<1, blk, 0, stream>>>(Wv, u0, sigma);

  // q = x @ Wq^T + bq -> out0 ; k = x @ Wk^T + bk -> out1
  gemm_mfma<true, false><<<dim3(2, 256, 1), blk, 0, stream>>>(x, Wq, out0, 0, 0, 0,
      bq, nullptr, 0, 0, nullptr, nullptr, nullptr);
  gemm_mfma<true, false><<<dim3(2, 256, 1), blk, 0, stream>>>(x, Wk, out1, 0, 0, 0,
      bk, nullptr, 0, 0, nullptr, nullptr, nullptr);

  // scores[b] = q[b] @ k[b]^T -> ws, fused norm slot 0
  gemm_mfma<true, true><<<dim3(512, 1, 1), blk, 0, stream>>>(out0, out1, scores_buf,
      MAT, MAT, MAT, nullptr, nullptr, 0, 0, norm2, nullptr, nullptr);

  // vals = (x @ Wv^T)/sigma + bv -> ws
  gemm_mfma<true, false><<<dim3(2, 256, 1), blk, 0, stream>>>(x, Wv, vals_buf, 0, 0, 0,
      bv, sigma, 0, 1, nullptr, nullptr, nullptr);

  // Gelfand chain: 12 normalized squarings ping-ponging out0/out1 (q,k dead)
  const float* cur = scores_buf;
  for (int i = 0; i < 12; i++) {
    float* cout = (i & 1) ? out1 : out0;
    gemm_mfma<false, true><<<dim3(512, 1, 1), blk, 0, stream>>>(cur, cur, cout,
        MAT, MAT, MAT, nullptr, norm2 + i * NB, 1, 1, norm2 + (i + 1) * NB,
        nullptr, nullptr);
    cur = cout;
  }
  finalize_rho<<<1, 128, 0, stream>>>(norm2, rho_inv);

  // weighted = (scores @ vals) * rho_inv -> out0 ;
  // attention = scores * rho_inv -> out1 (fused into A-staging of n0==0 blocks)
  gemm_mfma<false, true><<<dim3(512, 1, 1), blk, 0, stream>>>(scores_buf, vals_buf, out0,
      MAT, MAT, MAT, nullptr, rho_inv, 1, 2, nullptr, out1, rho_inv);
}